// Round 1
// baseline (648.592 us; speedup 1.0000x reference)
//
#include <hip/hip_runtime.h>

// QLSTM recurrence on MI355X.
// B=256 blocks x 64 threads: one wave per batch element, fully wave-synchronous
// (no barriers). Lane l owns h/c indices [4l..4l+3] and x indices [2l, 2l+1].
// Cross-lane reduction via DPP butterfly (no LDS round trips).

#define B_ 256
#define T_ 512
#define F_ 128
#define H_ 256

__device__ __forceinline__ float rcp_f(float x)  { return __builtin_amdgcn_rcpf(x); }
__device__ __forceinline__ float exp2_f(float x) { return __builtin_amdgcn_exp2f(x); }

// sigmoid(x) = 1/(1+e^-x); tanh(x) = 1 - 2/(1+e^{2x}). Both exact at +-inf
// through v_exp/v_rcp (rcp(inf)=0), no clamping needed. ~1 ulp vs 9.2e-3 tol.
__device__ __forceinline__ float sigmoid_f(float x) {
    return rcp_f(1.0f + exp2_f(-1.442695041f * x));
}
__device__ __forceinline__ float tanh_f(float x) {
    return 1.0f - 2.0f * rcp_f(1.0f + exp2_f(2.885390082f * x));
}

// v + dpp_permute(v). bound_ctrl=true -> invalid source lanes contribute 0.
template<int CTRL>
__device__ __forceinline__ float dpp_add(float v) {
    int p = __builtin_amdgcn_update_dpp(0, __float_as_int(v), CTRL, 0xf, 0xf, true);
    return v + __int_as_float(p);
}

// Full 64-lane sum, result broadcast via readlane(63) -> SGPR.
// Rounds: quad xor1 (0xB1), quad xor2 (0x4E), row_half_mirror (0x141, 8-wide),
// row_mirror (0x140, 16-wide), row_bcast15 (0x142), row_bcast31 (0x143).
__device__ __forceinline__ float wave_sum(float v) {
    v = dpp_add<0xB1>(v);
    v = dpp_add<0x4E>(v);
    v = dpp_add<0x141>(v);
    v = dpp_add<0x140>(v);
    v = dpp_add<0x142>(v);
    v = dpp_add<0x143>(v);
    return __int_as_float(__builtin_amdgcn_readlane(__float_as_int(v), 63));
}

__global__ __launch_bounds__(64, 1) void qlstm_kernel(
    const float* __restrict__ x,      // [B,T,F]
    const float* __restrict__ W_in,   // [H+F, 4] row-major (row = float4)
    const float* __restrict__ b_in,   // [4]
    const float* __restrict__ Wq,     // [4,4,4]
    const float* __restrict__ bq,     // [4,4]
    const float* __restrict__ W_out,  // [4,H]
    const float* __restrict__ b_out,  // [H]
    float* __restrict__ out)          // [B*T*H] ++ [B*H] ++ [B*H]
{
    const int b  = blockIdx.x;
    const int l  = threadIdx.x;  // 0..63
    const int i0 = l * 4;

    const float4* Win4 = (const float4*)W_in;  // 384 rows of float4

    // Per-lane recurrent weights: wh[j][q] = W_in[i0+j][q] (h part, rows 0..255)
    float wh[4][4];
#pragma unroll
    for (int j = 0; j < 4; ++j) {
        float4 t4 = Win4[i0 + j];
        wh[j][0] = t4.x; wh[j][1] = t4.y; wh[j][2] = t4.z; wh[j][3] = t4.w;
    }
    // Per-lane input weights: wx[j][q] = W_in[H + 2l + j][q]
    float wx[2][4];
#pragma unroll
    for (int j = 0; j < 2; ++j) {
        float4 t4 = Win4[H_ + 2 * l + j];
        wx[j][0] = t4.x; wx[j][1] = t4.y; wx[j][2] = t4.z; wx[j][3] = t4.w;
    }
    // Output-projection columns for my 4 h indices: wo[s][j] = W_out[s][i0+j]
    float wo[4][4];
#pragma unroll
    for (int s = 0; s < 4; ++s) {
        float4 t4 = ((const float4*)W_out)[s * (H_ / 4) + l];
        wo[s][0] = t4.x; wo[s][1] = t4.y; wo[s][2] = t4.z; wo[s][3] = t4.w;
    }
    float4 bo4 = ((const float4*)b_out)[l];
    float bov[4] = {bo4.x, bo4.y, bo4.z, bo4.w};

    // Uniform small tensors (uniform addresses -> scalar loads / SGPRs).
    float bin[4];
#pragma unroll
    for (int q = 0; q < 4; ++q) bin[q] = b_in[q];
    float wq[4][4][4];
#pragma unroll
    for (int k = 0; k < 4; ++k)
#pragma unroll
        for (int s = 0; s < 4; ++s)
#pragma unroll
            for (int r = 0; r < 4; ++r) wq[k][s][r] = Wq[k * 16 + s * 4 + r];
    float bqv[4][4];
#pragma unroll
    for (int k = 0; k < 4; ++k)
#pragma unroll
        for (int r = 0; r < 4; ++r) bqv[k][r] = bq[k * 4 + r];

    float h[4] = {0.f, 0.f, 0.f, 0.f};
    float c[4] = {0.f, 0.f, 0.f, 0.f};

    // x stream for this batch element: float2 per lane per step, coalesced.
    const float2* xr = (const float2*)(x + (size_t)b * T_ * F_) + l;
    float2 xv_next = xr[0];

    float* outb = out + ((size_t)b * T_) * H_ + i0;

    for (int t = 0; t < T_; ++t) {
        float2 xv = xv_next;
        int tn = (t + 1 < T_) ? (t + 1) : t;   // prefetch next step's x
        xv_next = xr[(size_t)tn * (F_ / 2)];

        // Partial y: h-part (4 owned) + x-part (2 owned), then wave reduce.
        float p[4];
#pragma unroll
        for (int q = 0; q < 4; ++q) {
            float a = fmaf(xv.x, wx[0][q], xv.y * wx[1][q]);
            a = fmaf(h[0], wh[0][q], a);
            a = fmaf(h[1], wh[1][q], a);
            a = fmaf(h[2], wh[2][q], a);
            a = fmaf(h[3], wh[3][q], a);
            p[q] = a;
        }
        float y[4];
#pragma unroll
        for (int q = 0; q < 4; ++q) y[q] = wave_sum(p[q]) + bin[q];

        // q[k][r] = tanh(sum_s y[s] * Wq[k][s][r] + bq[k][r])  (uniform)
        float qv[4][4];
#pragma unroll
        for (int k = 0; k < 4; ++k)
#pragma unroll
            for (int r = 0; r < 4; ++r) {
                float a = bqv[k][r];
                a = fmaf(y[0], wq[k][0][r], a);
                a = fmaf(y[1], wq[k][1][r], a);
                a = fmaf(y[2], wq[k][2][r], a);
                a = fmaf(y[3], wq[k][3][r], a);
                qv[k][r] = tanh_f(a);
            }

        // z, gates, state update for my 4 h indices.
#pragma unroll
        for (int j = 0; j < 4; ++j) {
            float z[4];
#pragma unroll
            for (int k = 0; k < 4; ++k) {
                float a = bov[j];
                a = fmaf(qv[k][0], wo[0][j], a);
                a = fmaf(qv[k][1], wo[1][j], a);
                a = fmaf(qv[k][2], wo[2][j], a);
                a = fmaf(qv[k][3], wo[3][j], a);
                z[k] = a;
            }
            float ig = sigmoid_f(z[0]);
            float fg = sigmoid_f(z[1]);
            float gg = tanh_f(z[2]);
            float og = sigmoid_f(z[3]);
            c[j] = fmaf(fg, c[j], ig * gg);
            h[j] = og * tanh_f(c[j]);
        }

        float4 hv = {h[0], h[1], h[2], h[3]};
        *(float4*)(outb + (size_t)t * H_) = hv;  // coalesced 1 KiB/wave store
    }

    // Final states: h_T then c_T after hidden_seq.
    float* hT = out + (size_t)B_ * T_ * H_;
    float* cT = hT + (size_t)B_ * H_;
    float4 hv = {h[0], h[1], h[2], h[3]};
    float4 cv = {c[0], c[1], c[2], c[3]};
    *(float4*)(hT + (size_t)b * H_ + i0) = hv;
    *(float4*)(cT + (size_t)b * H_ + i0) = cv;
}

extern "C" void kernel_launch(void* const* d_in, const int* in_sizes, int n_in,
                              void* d_out, int out_size, void* d_ws, size_t ws_size,
                              hipStream_t stream) {
    const float* x     = (const float*)d_in[0];
    const float* W_in  = (const float*)d_in[1];
    const float* b_in  = (const float*)d_in[2];
    const float* Wq    = (const float*)d_in[3];
    const float* bq    = (const float*)d_in[4];
    const float* W_out = (const float*)d_in[5];
    const float* b_out = (const float*)d_in[6];
    float* out = (float*)d_out;

    qlstm_kernel<<<dim3(B_), dim3(64), 0, stream>>>(
        x, W_in, b_in, Wq, bq, W_out, b_out, out);
}

// Round 2
// 390.559 us; speedup vs baseline: 1.6607x; 1.6607x over previous
//
#include <hip/hip_runtime.h>

// QLSTM recurrence on MI355X — round 2.
// 256 blocks x 256 threads: one BLOCK per batch element, 4 waves = 4 SIMDs/CU.
// Lane g (=threadIdx.x) owns h index g (1 of 256); lanes g<128 (waves 0,1)
// also own x index g. Per step:
//   - per-wave DPP butterfly reduces the 64-lane partial of y[0..3]
//   - lane 63 of each wave writes its float4 partial to LDS (double-buffered
//     by t&1 -> ONE __syncthreads per step is sufficient)
//   - all lanes read the 4 partials (broadcast, conflict-free), get uniform y
//   - the 16-entry tanh q-block is computed by lanes l&15 (one tanh each) and
//     broadcast via 16 constant-lane readlanes into SGPRs (kills the 16
//     redundant tanh pairs/lane of round 1)
//   - each lane computes z[0..3], gates, c/h update for its single h index
//     (5 transcendental pairs/lane vs 20 in round 1)

#define B_ 256
#define T_ 512
#define F_ 128
#define H_ 256

__device__ __forceinline__ float rcp_f(float x)  { return __builtin_amdgcn_rcpf(x); }
__device__ __forceinline__ float exp2_f(float x) { return __builtin_amdgcn_exp2f(x); }

// sigmoid(x) = 1/(1+e^-x); tanh(x) = 1 - 2/(1+e^{2x}). Exact at +-inf via
// v_exp/v_rcp (rcp(inf)=0). absmax 9.8e-4 vs 9.2e-3 threshold in round 1.
__device__ __forceinline__ float sigmoid_f(float x) {
    return rcp_f(1.0f + exp2_f(-1.442695041f * x));
}
__device__ __forceinline__ float tanh_f(float x) {
    return 1.0f - 2.0f * rcp_f(1.0f + exp2_f(2.885390082f * x));
}

template<int CTRL>
__device__ __forceinline__ float dpp_add(float v) {
    int p = __builtin_amdgcn_update_dpp(0, __float_as_int(v), CTRL, 0xf, 0xf, true);
    return v + __int_as_float(p);
}

// 64-lane sum; result valid at LANE 63 only (no readlane — lane 63 writes LDS).
// xor1, xor2, row_half_mirror, row_mirror, row_bcast15, row_bcast31.
__device__ __forceinline__ float wave_sum63(float v) {
    v = dpp_add<0xB1>(v);
    v = dpp_add<0x4E>(v);
    v = dpp_add<0x141>(v);
    v = dpp_add<0x140>(v);
    v = dpp_add<0x142>(v);
    v = dpp_add<0x143>(v);
    return v;
}

__global__ __launch_bounds__(256, 1) void qlstm_kernel(
    const float* __restrict__ x,      // [B,T,F]
    const float* __restrict__ W_in,   // [H+F, 4] (row = float4)
    const float* __restrict__ b_in,   // [4]
    const float* __restrict__ Wq,     // [4,4,4]
    const float* __restrict__ bq,     // [4,4]
    const float* __restrict__ W_out,  // [4,H]
    const float* __restrict__ b_out,  // [H]
    float* __restrict__ out)          // [B*T*H] ++ [B*H] ++ [B*H]
{
    const int b = blockIdx.x;
    const int g = threadIdx.x;   // 0..255 — my h index
    const int w = g >> 6;        // wave 0..3
    const int l = g & 63;

    __shared__ float4 part[2][4];  // [t&1][wave] y-partials

    const float4* Win4 = (const float4*)W_in;

    // Recurrent weight row for my h index.
    float4 t4 = Win4[g];
    float wh[4] = {t4.x, t4.y, t4.z, t4.w};

    // Input weight row for my x index (waves 0,1 only — wave-uniform branch).
    const bool has_x = (w < 2);
    float wx[4] = {0.f, 0.f, 0.f, 0.f};
    if (has_x) {
        float4 u4 = Win4[H_ + g];
        wx[0] = u4.x; wx[1] = u4.y; wx[2] = u4.z; wx[3] = u4.w;
    }

    // Output-projection column for my h index + bias.
    float wo[4];
#pragma unroll
    for (int r = 0; r < 4; ++r) wo[r] = W_out[r * H_ + g];
    const float bo = b_out[g];

    // Uniform b_in (folded into the q-block bias below).
    float bin[4];
#pragma unroll
    for (int q = 0; q < 4; ++q) bin[q] = b_in[q];

    // Lane-distributed q-block weights: lane m=l&15 owns (k,r)=(m>>2, m&3).
    const int m = l & 15, qk = m >> 2, qr = m & 3;
    float wql[4];
#pragma unroll
    for (int s = 0; s < 4; ++s) wql[s] = Wq[qk * 16 + s * 4 + qr];
    float bql = bq[qk * 4 + qr];
#pragma unroll
    for (int s = 0; s < 4; ++s) bql = fmaf(bin[s], wql[s], bql);  // fold b_in

    float h = 0.f, c = 0.f;

    // x stream: one float per lane per step for lanes g<128 (coalesced).
    const float* xp = x + (size_t)b * T_ * F_ + g;
    float xv_next = has_x ? xp[0] : 0.f;

    float* outp = out + (size_t)b * T_ * H_ + g;

    for (int t = 0; t < T_; ++t) {
        const float xv = xv_next;
        if (has_x) {
            int tn = (t + 1 < T_) ? (t + 1) : t;
            xv_next = xp[(size_t)tn * F_];
        }

        // Per-lane y partials (1 h row + optionally 1 x row), wave-reduce.
        float p0 = fmaf(h, wh[0], xv * wx[0]);
        float p1 = fmaf(h, wh[1], xv * wx[1]);
        float p2 = fmaf(h, wh[2], xv * wx[2]);
        float p3 = fmaf(h, wh[3], xv * wx[3]);
        p0 = wave_sum63(p0);
        p1 = wave_sum63(p1);
        p2 = wave_sum63(p2);
        p3 = wave_sum63(p3);
        if (l == 63) part[t & 1][w] = make_float4(p0, p1, p2, p3);
        __syncthreads();
        float4 a0 = part[t & 1][0];
        float4 a1 = part[t & 1][1];
        float4 a2 = part[t & 1][2];
        float4 a3 = part[t & 1][3];
        const float y0 = (a0.x + a1.x) + (a2.x + a3.x);  // raw (b_in folded)
        const float y1 = (a0.y + a1.y) + (a2.y + a3.y);
        const float y2 = (a0.z + a1.z) + (a2.z + a3.z);
        const float y3 = (a0.w + a1.w) + (a2.w + a3.w);

        // q-block: lane l&15 computes tanh for its (k,r); broadcast 16 lanes.
        float aq = bql;
        aq = fmaf(y0, wql[0], aq);
        aq = fmaf(y1, wql[1], aq);
        aq = fmaf(y2, wql[2], aq);
        aq = fmaf(y3, wql[3], aq);
        const float qown = tanh_f(aq);
        float qs[16];
#pragma unroll
        for (int i = 0; i < 16; ++i)
            qs[i] = __int_as_float(
                __builtin_amdgcn_readlane(__float_as_int(qown), i));

        // z[k] = b_out[g] + sum_r qs[k*4+r] * wo[r]; gates; state update.
        float z[4];
#pragma unroll
        for (int k = 0; k < 4; ++k) {
            float a = bo;
            a = fmaf(qs[k * 4 + 0], wo[0], a);
            a = fmaf(qs[k * 4 + 1], wo[1], a);
            a = fmaf(qs[k * 4 + 2], wo[2], a);
            a = fmaf(qs[k * 4 + 3], wo[3], a);
            z[k] = a;
        }
        const float ig = sigmoid_f(z[0]);
        const float fg = sigmoid_f(z[1]);
        const float gg = tanh_f(z[2]);
        const float og = sigmoid_f(z[3]);
        c = fmaf(fg, c, ig * gg);
        h = og * tanh_f(c);

        outp[(size_t)t * H_] = h;  // 1 KiB coalesced store per block-step
    }

    // Final states: h_T then c_T after hidden_seq.
    float* hT = out + (size_t)B_ * T_ * H_;
    hT[(size_t)b * H_ + g] = h;
    hT[(size_t)B_ * H_ + (size_t)b * H_ + g] = c;
}

extern "C" void kernel_launch(void* const* d_in, const int* in_sizes, int n_in,
                              void* d_out, int out_size, void* d_ws, size_t ws_size,
                              hipStream_t stream) {
    const float* x     = (const float*)d_in[0];
    const float* W_in  = (const float*)d_in[1];
    const float* b_in  = (const float*)d_in[2];
    const float* Wq    = (const float*)d_in[3];
    const float* bq    = (const float*)d_in[4];
    const float* W_out = (const float*)d_in[5];
    const float* b_out = (const float*)d_in[6];
    float* out = (float*)d_out;

    qlstm_kernel<<<dim3(B_), dim3(256), 0, stream>>>(
        x, W_in, b_in, Wq, bq, W_out, b_out, out);
}

// Round 3
// 390.099 us; speedup vs baseline: 1.6626x; 1.0012x over previous
//
#include <hip/hip_runtime.h>

// QLSTM recurrence on MI355X — round 3.
// Same structure as round 2 (256 blocks x 256 threads, one block per batch
// element, lane g owns h index g, per-wave DPP reduce + LDS exchange of y
// partials, lane-distributed q-tanh + readlane broadcast).
//
// Round-3 change: __syncthreads() -> raw `s_waitcnt lgkmcnt(0); s_barrier`.
// __syncthreads lowers to s_waitcnt vmcnt(0) lgkmcnt(0) + s_barrier, which
// forcibly retires the per-step global store AND the x prefetch load into the
// serial chain (~500+ cyc/step). The raw barrier drains only LDS (lgkmcnt);
// correctness: cross-wave data is LDS-only; writer drains its ds_write before
// the barrier; readers get compiler lgkm waits before use; global accesses
// are per-lane disjoint. Double-buffer by t&1 keeps one barrier/step safe.

#define B_ 256
#define T_ 512
#define F_ 128
#define H_ 256

__device__ __forceinline__ float rcp_f(float x)  { return __builtin_amdgcn_rcpf(x); }
__device__ __forceinline__ float exp2_f(float x) { return __builtin_amdgcn_exp2f(x); }

__device__ __forceinline__ float sigmoid_f(float x) {
    return rcp_f(1.0f + exp2_f(-1.442695041f * x));
}
__device__ __forceinline__ float tanh_f(float x) {
    return 1.0f - 2.0f * rcp_f(1.0f + exp2_f(2.885390082f * x));
}

template<int CTRL>
__device__ __forceinline__ float dpp_add(float v) {
    int p = __builtin_amdgcn_update_dpp(0, __float_as_int(v), CTRL, 0xf, 0xf, true);
    return v + __int_as_float(p);
}

// 64-lane sum; result valid at LANE 63 only.
__device__ __forceinline__ float wave_sum63(float v) {
    v = dpp_add<0xB1>(v);    // xor 1
    v = dpp_add<0x4E>(v);    // xor 2
    v = dpp_add<0x141>(v);   // row_half_mirror
    v = dpp_add<0x140>(v);   // row_mirror
    v = dpp_add<0x142>(v);   // row_bcast15
    v = dpp_add<0x143>(v);   // row_bcast31
    return v;
}

// LDS-only barrier: drain LDS ops, sync waves. Does NOT drain vmcnt — global
// stores/prefetches stay in flight across it (the round-3 win).
__device__ __forceinline__ void lds_barrier() {
    asm volatile("s_waitcnt lgkmcnt(0)\n\ts_barrier" ::: "memory");
}

__global__ __launch_bounds__(256, 1) void qlstm_kernel(
    const float* __restrict__ x,      // [B,T,F]
    const float* __restrict__ W_in,   // [H+F, 4] (row = float4)
    const float* __restrict__ b_in,   // [4]
    const float* __restrict__ Wq,     // [4,4,4]
    const float* __restrict__ bq,     // [4,4]
    const float* __restrict__ W_out,  // [4,H]
    const float* __restrict__ b_out,  // [H]
    float* __restrict__ out)          // [B*T*H] ++ [B*H] ++ [B*H]
{
    const int b = blockIdx.x;
    const int g = threadIdx.x;   // 0..255 — my h index
    const int w = g >> 6;        // wave 0..3
    const int l = g & 63;

    __shared__ float4 part[2][4];  // [t&1][wave] y-partials

    const float4* Win4 = (const float4*)W_in;

    float4 t4 = Win4[g];
    float wh[4] = {t4.x, t4.y, t4.z, t4.w};

    const bool has_x = (w < 2);
    float wx[4] = {0.f, 0.f, 0.f, 0.f};
    if (has_x) {
        float4 u4 = Win4[H_ + g];
        wx[0] = u4.x; wx[1] = u4.y; wx[2] = u4.z; wx[3] = u4.w;
    }

    float wo[4];
#pragma unroll
    for (int r = 0; r < 4; ++r) wo[r] = W_out[r * H_ + g];
    const float bo = b_out[g];

    float bin[4];
#pragma unroll
    for (int q = 0; q < 4; ++q) bin[q] = b_in[q];

    // Lane-distributed q-block: lane m=l&15 owns (k,r)=(m>>2, m&3).
    const int m = l & 15, qk = m >> 2, qr = m & 3;
    float wql[4];
#pragma unroll
    for (int s = 0; s < 4; ++s) wql[s] = Wq[qk * 16 + s * 4 + qr];
    float bql = bq[qk * 4 + qr];
#pragma unroll
    for (int s = 0; s < 4; ++s) bql = fmaf(bin[s], wql[s], bql);  // fold b_in

    float h = 0.f, c = 0.f;

    const float* xp = x + (size_t)b * T_ * F_ + g;
    float xv_next = has_x ? xp[0] : 0.f;

    float* outp = out + (size_t)b * T_ * H_ + g;

    for (int t = 0; t < T_; ++t) {
        const float xv = xv_next;
        if (has_x) {
            int tn = (t + 1 < T_) ? (t + 1) : t;
            xv_next = xp[(size_t)tn * F_];   // stays in flight across barrier
        }

        float p0 = fmaf(h, wh[0], xv * wx[0]);
        float p1 = fmaf(h, wh[1], xv * wx[1]);
        float p2 = fmaf(h, wh[2], xv * wx[2]);
        float p3 = fmaf(h, wh[3], xv * wx[3]);
        p0 = wave_sum63(p0);
        p1 = wave_sum63(p1);
        p2 = wave_sum63(p2);
        p3 = wave_sum63(p3);
        if (l == 63) part[t & 1][w] = make_float4(p0, p1, p2, p3);
        lds_barrier();
        float4 a0 = part[t & 1][0];
        float4 a1 = part[t & 1][1];
        float4 a2 = part[t & 1][2];
        float4 a3 = part[t & 1][3];
        const float y0 = (a0.x + a1.x) + (a2.x + a3.x);
        const float y1 = (a0.y + a1.y) + (a2.y + a3.y);
        const float y2 = (a0.z + a1.z) + (a2.z + a3.z);
        const float y3 = (a0.w + a1.w) + (a2.w + a3.w);

        float aq = bql;
        aq = fmaf(y0, wql[0], aq);
        aq = fmaf(y1, wql[1], aq);
        aq = fmaf(y2, wql[2], aq);
        aq = fmaf(y3, wql[3], aq);
        const float qown = tanh_f(aq);
        float qs[16];
#pragma unroll
        for (int i = 0; i < 16; ++i)
            qs[i] = __int_as_float(
                __builtin_amdgcn_readlane(__float_as_int(qown), i));

        float z[4];
#pragma unroll
        for (int k = 0; k < 4; ++k) {
            float a = bo;
            a = fmaf(qs[k * 4 + 0], wo[0], a);
            a = fmaf(qs[k * 4 + 1], wo[1], a);
            a = fmaf(qs[k * 4 + 2], wo[2], a);
            a = fmaf(qs[k * 4 + 3], wo[3], a);
            z[k] = a;
        }
        const float ig = sigmoid_f(z[0]);
        const float fg = sigmoid_f(z[1]);
        const float gg = tanh_f(z[2]);
        const float og = sigmoid_f(z[3]);
        c = fmaf(fg, c, ig * gg);
        h = og * tanh_f(c);

        outp[(size_t)t * H_] = h;  // floats free past the raw barrier
    }

    float* hT = out + (size_t)B_ * T_ * H_;
    hT[(size_t)b * H_ + g] = h;
    hT[(size_t)B_ * H_ + (size_t)b * H_ + g] = c;
}

extern "C" void kernel_launch(void* const* d_in, const int* in_sizes, int n_in,
                              void* d_out, int out_size, void* d_ws, size_t ws_size,
                              hipStream_t stream) {
    const float* x     = (const float*)d_in[0];
    const float* W_in  = (const float*)d_in[1];
    const float* b_in  = (const float*)d_in[2];
    const float* Wq    = (const float*)d_in[3];
    const float* bq    = (const float*)d_in[4];
    const float* W_out = (const float*)d_in[5];
    const float* b_out = (const float*)d_in[6];
    float* out = (float*)d_out;

    qlstm_kernel<<<dim3(B_), dim3(256), 0, stream>>>(
        x, W_in, b_in, Wq, bq, W_out, b_out, out);
}